// Round 7
// baseline (106.793 us; speedup 1.0000x reference)
//
#include <hip/hip_runtime.h>
#include <math.h>

#define N 8192
#define D 64
#define CHUNKS 512
#define CROWS 16
#define KS 32       // key slices
#define SLICE 256   // N / KS
#define NQ (2 * N)  // 8192 element-rank queries + 8192 row-threshold queries
#define QPT 8       // queries per thread in k2a

typedef unsigned long long u64;

__device__ __forceinline__ unsigned ordered_bits(float v) {
  unsigned u = __float_as_uint(v);
  return u ^ (((int)u >> 31) | 0x80000000u);
}

// K1: h = x@Wt (Wt column in regs, x row via shfl broadcast); f1/f2; 64-bit
// strictly-distinct sort keys + per-row threshold keys. 32 rows/block.
__global__ __launch_bounds__(256) void k1_gemm(
    const float* __restrict__ x, const float* __restrict__ Wt,
    const float* __restrict__ a1, const float* __restrict__ b1,
    const float* __restrict__ a2, const float* __restrict__ b2,
    float* __restrict__ h, float* __restrict__ f1, float* __restrict__ f2,
    u64* __restrict__ key64, u64* __restrict__ thrkey) {
  int t = threadIdx.x;
  int lane = t & 63, wv = t >> 6;
  float wcol[D];
#pragma unroll
  for (int k = 0; k < D; ++k) wcol[k] = Wt[k * D + lane];  // coalesced
  float a1d = a1[lane], a2d = a2[lane];
  float b1v = b1[0], b2v = b2[0];
  int rowBase = blockIdx.x * 32;
#pragma unroll
  for (int it = 0; it < 8; ++it) {
    int grow = rowBase + wv + it * 4;
    float xv = x[grow * D + lane];
    float acc = 0.f;
#pragma unroll
    for (int k = 0; k < D; ++k) acc += __shfl(xv, k) * wcol[k];
    h[grow * D + lane] = acc;
    float v1 = acc * a1d, v2 = acc * a2d;
#pragma unroll
    for (int off = 32; off > 0; off >>= 1) {
      v1 += __shfl_xor(v1, off);
      v2 += __shfl_xor(v2, off);
    }
    if (lane == 0) {
      float F1 = v1 + b1v, F2 = v2 + b2v;
      f1[grow] = F1;
      f2[grow] = F2;
      key64[grow] = ((u64)ordered_bits(F2) << 13) | (unsigned)grow;
      thrkey[grow] = ((u64)ordered_bits(-F1) << 13);
    }
  }
}

// K2a: partial counting rank. Block (g,s): query group g (2048 queries,
// 8/thread) vs key slice s (256 keys in LDS). part[s][q] = partial count.
__global__ __launch_bounds__(256) void k2a_count(
    const u64* __restrict__ key64, const u64* __restrict__ thrkey,
    int* __restrict__ part) {
  __shared__ u64 ksl[SLICE];
  int t = threadIdx.x;
  int g = blockIdx.x >> 5;        // 0..7
  int s = blockIdx.x & (KS - 1);  // 0..31
  ksl[t] = key64[s * SLICE + t];
  int q0 = g * (QPT * 256) + t;
  u64 qk[QPT];
#pragma unroll
  for (int i = 0; i < QPT; ++i) {
    int q = q0 + i * 256;
    qk[i] = (q < N) ? key64[q] : thrkey[q - N];
  }
  __syncthreads();
  int cnt[QPT] = {0, 0, 0, 0, 0, 0, 0, 0};
#pragma unroll 4
  for (int l = 0; l < SLICE; ++l) {
    u64 k = ksl[l];
#pragma unroll
    for (int i = 0; i < QPT; ++i) cnt[i] += (k < qk[i]) ? 1 : 0;
  }
  int* pb = part + s * NQ;
#pragma unroll
  for (int i = 0; i < QPT; ++i) pb[q0 + i * 256] = cnt[i];
}

// K2b: reduce KS partials per query; scatter perm/weights or write ksplit.
__global__ __launch_bounds__(256) void k2b_reduce(
    const int* __restrict__ part, const float* __restrict__ f2,
    int* __restrict__ perm, float* __restrict__ wsm, float* __restrict__ wbg,
    int* __restrict__ ksplit) {
  int q = blockIdx.x * 256 + threadIdx.x;
  int tot = 0;
#pragma unroll
  for (int s = 0; s < KS; ++s) tot += part[s * NQ + q];
  if (q < N) {
    float v = f2[q];
    perm[tot] = q;
    wsm[tot] = expf(0.2f * v);
    wbg[tot] = expf(v);
  } else {
    ksplit[q - N] = tot;
  }
}

// K3: per-chunk LOCAL scans (1 chunk per wave, registers only) + totals.
__global__ __launch_bounds__(256) void k3_scan(
    const float* __restrict__ h, const int* __restrict__ perm,
    const float* __restrict__ wsm, const float* __restrict__ wbg,
    float* __restrict__ Pl, float* __restrict__ Sl,
    float* __restrict__ pl, float* __restrict__ sl,
    float* __restrict__ tot_s, float* __restrict__ tot_b,
    float* __restrict__ tots_sc, float* __restrict__ totb_sc) {
  int t = threadIdx.x, lane = t & 63, wv = t >> 6;
  int c = blockIdx.x * 4 + wv;
  int base = c * CROWS;
  int dd = lane;
  int pj = (dd < CROWS) ? perm[base + dd] : 0;
  float wS = (dd < CROWS) ? wsm[base + dd] : 0.f;
  float wB = (dd < CROWS) ? wbg[base + dd] : 0.f;
  float hv[CROWS];
#pragma unroll
  for (int r = 0; r < CROWS; ++r) {
    int j = __shfl(pj, r);
    hv[r] = h[(size_t)j * D + dd];
  }
  // scalar weight scans over lanes 0..15
  float incS = wS, incB = wB;
#pragma unroll
  for (int off = 1; off < CROWS; off <<= 1) {
    float uS = __shfl_up(incS, off);
    float uB = __shfl_up(incB, off);
    if (dd >= off) { incS += uS; incB += uB; }
  }
  float totS = __shfl(incS, CROWS - 1);
  float totB = __shfl(incB, CROWS - 1);
  if (dd < CROWS) {
    pl[base + dd] = incS - wS;           // exclusive prefix (small w)
    sl[base + dd] = totB - (incB - wB);  // inclusive suffix (big w)
  }
  if (dd == 0) { tots_sc[c] = totS; totb_sc[c] = totB; }
  // vector local scans (registers only)
  float runP = 0.f;
#pragma unroll
  for (int r = 0; r < CROWS; ++r) {
    Pl[(size_t)(base + r) * D + dd] = runP;
    runP += __shfl(wS, r) * hv[r];
  }
  tot_s[c * D + dd] = runP;
  float runS = 0.f;
#pragma unroll
  for (int r = CROWS - 1; r >= 0; --r) {
    runS += __shfl(wB, r) * hv[r];
    Sl[(size_t)(base + r) * D + dd] = runS;
  }
  tot_b[c * D + dd] = runS;
}

// K3b: chunk-offset scans, fully parallel. Blocks 0..63: vector prefix for
// dim=blk; 64..127: vector exclusive suffix for dim=blk-64; 128: scalars.
// 512-wide Hillis-Steele in LDS (9 steps).
__global__ __launch_bounds__(512) void k3b_offsets(
    const float* __restrict__ tot_s, const float* __restrict__ tot_b,
    const float* __restrict__ tots_sc, const float* __restrict__ totb_sc,
    float* __restrict__ off_s, float* __restrict__ off_b,
    float* __restrict__ poff, float* __restrict__ soff,
    float* __restrict__ Pl, float* __restrict__ Sl,
    float* __restrict__ pl, float* __restrict__ sl) {
  __shared__ float sc[512];
  int t = threadIdx.x;
  int blk = blockIdx.x;
  if (blk < 64) {
    int dd = blk;
    float v = tot_s[t * D + dd];
    sc[t] = v;
    __syncthreads();
    float inc = v;
#pragma unroll
    for (int off = 1; off < 512; off <<= 1) {
      float u_ = (t >= off) ? sc[t - off] : 0.f;
      __syncthreads();
      inc += u_;
      sc[t] = inc;
      __syncthreads();
    }
    off_s[t * D + dd] = inc - v;
    if (t == 511) off_s[CHUNKS * D + dd] = inc;  // sentinel
    if (t == 0) Pl[(size_t)N * D + dd] = 0.f;
  } else if (blk < 128) {
    int dd = blk - 64;
    int rc = 511 - t;
    float v = tot_b[rc * D + dd];
    sc[t] = v;
    __syncthreads();
    float inc = v;
#pragma unroll
    for (int off = 1; off < 512; off <<= 1) {
      float u_ = (t >= off) ? sc[t - off] : 0.f;
      __syncthreads();
      inc += u_;
      sc[t] = inc;
      __syncthreads();
    }
    off_b[rc * D + dd] = inc - v;  // exclusive suffix
    if (t == 0) {
      off_b[CHUNKS * D + dd] = 0.f;  // sentinel
      Sl[(size_t)N * D + dd] = 0.f;
    }
  } else {
    {  // scalar prefix over tots_sc
      float v = tots_sc[t];
      sc[t] = v;
      __syncthreads();
      float inc = v;
#pragma unroll
      for (int off = 1; off < 512; off <<= 1) {
        float u_ = (t >= off) ? sc[t - off] : 0.f;
        __syncthreads();
        inc += u_;
        sc[t] = inc;
        __syncthreads();
      }
      poff[t] = inc - v;
      if (t == 511) poff[CHUNKS] = inc;
      if (t == 0) pl[N] = 0.f;
    }
    __syncthreads();
    {  // scalar exclusive suffix over totb_sc
      int rc = 511 - t;
      float v = totb_sc[rc];
      sc[t] = v;
      __syncthreads();
      float inc = v;
#pragma unroll
      for (int off = 1; off < 512; off <<= 1) {
        float u_ = (t >= off) ? sc[t - off] : 0.f;
        __syncthreads();
        inc += u_;
        sc[t] = inc;
        __syncthreads();
      }
      soff[rc] = inc - v;
      if (t == 0) {
        soff[CHUNKS] = 0.f;
        sl[N] = 0.f;
      }
    }
  }
}

// K4: per (row, dim): combine global offset + local scan at split k; ELU.
__global__ __launch_bounds__(256) void k4_out(
    const float* __restrict__ f1, const int* __restrict__ ksplit,
    const float* __restrict__ off_s, const float* __restrict__ off_b,
    const float* __restrict__ poff, const float* __restrict__ soff,
    const float* __restrict__ Pl, const float* __restrict__ Sl,
    const float* __restrict__ pl, const float* __restrict__ sl,
    float* __restrict__ out) {
  int g = blockIdx.x * 256 + threadIdx.x;
  int row = g >> 6, dd = g & 63;
  float f1v = f1[row];
  int k = ksplit[row];
  int c = k >> 4;  // CROWS == 16; k == N -> sentinel chunk
  float e1 = expf(f1v), e2 = expf(0.2f * f1v);
  float Sv = off_b[c * D + dd] + Sl[(size_t)k * D + dd];
  float Pv = off_s[c * D + dd] + Pl[(size_t)k * D + dd];
  float num = e1 * Sv + e2 * Pv;
  float den = e1 * (soff[c] + sl[k]) + e2 * (poff[c] + pl[k]);
  float v = num / den;
  out[g] = v > 0.f ? v : expm1f(v);
}

extern "C" void kernel_launch(void* const* d_in, const int* in_sizes, int n_in,
                              void* d_out, int out_size, void* d_ws,
                              size_t ws_size, hipStream_t stream) {
  const float* x = (const float*)d_in[0];
  const float* Wt = (const float*)d_in[1];
  const float* a1 = (const float*)d_in[2];
  const float* b1 = (const float*)d_in[3];
  const float* a2 = (const float*)d_in[4];
  const float* b2 = (const float*)d_in[5];
  float* out = (float*)d_out;

  u64* key64 = (u64*)d_ws;
  u64* thrkey = key64 + N;
  float* ws = (float*)(thrkey + N);
  float* h = ws;          ws += N * D;
  float* f1 = ws;         ws += N;
  float* f2v = ws;        ws += N;
  float* wsm = ws;        ws += N;
  float* wbg = ws;        ws += N;
  int* perm = (int*)ws;   ws += N;
  int* ksplit = (int*)ws; ws += N;
  int* part = (int*)ws;   ws += KS * NQ;
  float* Pl = ws;         ws += (size_t)(N + 1) * D;
  float* Sl = ws;         ws += (size_t)(N + 1) * D;
  float* tot_s = ws;      ws += CHUNKS * D;
  float* tot_b = ws;      ws += CHUNKS * D;
  float* off_s = ws;      ws += (CHUNKS + 1) * D;
  float* off_b = ws;      ws += (CHUNKS + 1) * D;
  float* pl = ws;         ws += (N + 1);
  float* sl = ws;         ws += (N + 1);
  float* tots_sc = ws;    ws += CHUNKS;
  float* totb_sc = ws;    ws += CHUNKS;
  float* poff = ws;       ws += (CHUNKS + 1);
  float* soff = ws;       ws += (CHUNKS + 1);

  k1_gemm<<<N / 32, 256, 0, stream>>>(x, Wt, a1, b1, a2, b2, h, f1, f2v,
                                      key64, thrkey);
  k2a_count<<<8 * KS, 256, 0, stream>>>(key64, thrkey, part);
  k2b_reduce<<<NQ / 256, 256, 0, stream>>>(part, f2v, perm, wsm, wbg, ksplit);
  k3_scan<<<CHUNKS / 4, 256, 0, stream>>>(h, perm, wsm, wbg, Pl, Sl, pl, sl,
                                          tot_s, tot_b, tots_sc, totb_sc);
  k3b_offsets<<<129, 512, 0, stream>>>(tot_s, tot_b, tots_sc, totb_sc, off_s,
                                       off_b, poff, soff, Pl, Sl, pl, sl);
  k4_out<<<(N * D) / 256, 256, 0, stream>>>(f1, ksplit, off_s, off_b, poff,
                                            soff, Pl, Sl, pl, sl, out);
}

// Round 8
// 99.366 us; speedup vs baseline: 1.0747x; 1.0747x over previous
//
#include <hip/hip_runtime.h>
#include <math.h>

#define N 8192
#define D 64
#define CHUNKS 512
#define CROWS 16
#define KS 32       // key slices
#define SLICE 256   // N / KS
#define NQ (2 * N)  // 8192 element-rank queries + 8192 row-threshold queries

typedef unsigned long long u64;

__device__ __forceinline__ unsigned ordered_bits(float v) {
  unsigned u = __float_as_uint(v);
  return u ^ (((int)u >> 31) | 0x80000000u);
}

// K1: h = x@Wt (Wt column in regs, x row via shfl broadcast); f1/f2; 64-bit
// strictly-distinct sort keys + per-row threshold keys. 16 rows/block
// (512 blocks — more, smaller blocks drain faster; R7 showed 32/block regresses).
__global__ __launch_bounds__(256) void k1_gemm(
    const float* __restrict__ x, const float* __restrict__ Wt,
    const float* __restrict__ a1, const float* __restrict__ b1,
    const float* __restrict__ a2, const float* __restrict__ b2,
    float* __restrict__ h, float* __restrict__ f1, float* __restrict__ f2,
    u64* __restrict__ key64, u64* __restrict__ thrkey) {
  int t = threadIdx.x;
  int lane = t & 63, wv = t >> 6;
  float wcol[D];
#pragma unroll
  for (int k = 0; k < D; ++k) wcol[k] = Wt[k * D + lane];  // coalesced
  float a1d = a1[lane], a2d = a2[lane];
  float b1v = b1[0], b2v = b2[0];
  int rowBase = blockIdx.x * 16;
#pragma unroll
  for (int it = 0; it < 4; ++it) {
    int grow = rowBase + wv + it * 4;
    float xv = x[grow * D + lane];
    float acc = 0.f;
#pragma unroll
    for (int k = 0; k < D; ++k) acc += __shfl(xv, k) * wcol[k];
    h[grow * D + lane] = acc;
    float v1 = acc * a1d, v2 = acc * a2d;
#pragma unroll
    for (int off = 32; off > 0; off >>= 1) {
      v1 += __shfl_xor(v1, off);
      v2 += __shfl_xor(v2, off);
    }
    if (lane == 0) {
      float F1 = v1 + b1v, F2 = v2 + b2v;
      f1[grow] = F1;
      f2[grow] = F2;
      key64[grow] = ((u64)ordered_bits(F2) << 13) | (unsigned)grow;
      thrkey[grow] = ((u64)ordered_bits(-F1) << 13);
    }
  }
}

// K2a: partial counting rank. Block (g,s): query group g (1024 queries,
// 4/thread) vs key slice s (256 keys in LDS). part[s][q] = partial count.
// 512 blocks / 4 q-per-thread is the measured optimum (R6 vs R7).
__global__ __launch_bounds__(256) void k2a_count(
    const u64* __restrict__ key64, const u64* __restrict__ thrkey,
    int* __restrict__ part) {
  __shared__ u64 ksl[SLICE];
  int t = threadIdx.x;
  int g = blockIdx.x >> 5;        // 0..15
  int s = blockIdx.x & (KS - 1);  // 0..31
  ksl[t] = key64[s * SLICE + t];
  int q0 = g * 1024 + t;
  u64 qa = (q0 < N) ? key64[q0] : thrkey[q0 - N];
  int q1 = q0 + 256;
  u64 qb = (q1 < N) ? key64[q1] : thrkey[q1 - N];
  int q2 = q0 + 512;
  u64 qc = (q2 < N) ? key64[q2] : thrkey[q2 - N];
  int q3 = q0 + 768;
  u64 qd = (q3 < N) ? key64[q3] : thrkey[q3 - N];
  __syncthreads();
  int c0 = 0, c1 = 0, c2 = 0, c3 = 0;
#pragma unroll 8
  for (int l = 0; l < SLICE; ++l) {
    u64 k = ksl[l];
    c0 += (k < qa) ? 1 : 0;
    c1 += (k < qb) ? 1 : 0;
    c2 += (k < qc) ? 1 : 0;
    c3 += (k < qd) ? 1 : 0;
  }
  int* pb = part + s * NQ;
  pb[q0] = c0;
  pb[q1] = c1;
  pb[q2] = c2;
  pb[q3] = c3;
}

// K2b: reduce KS partials per query; scatter perm/weights or write ksplit.
__global__ __launch_bounds__(256) void k2b_reduce(
    const int* __restrict__ part, const float* __restrict__ f2,
    int* __restrict__ perm, float* __restrict__ wsm, float* __restrict__ wbg,
    int* __restrict__ ksplit) {
  int q = blockIdx.x * 256 + threadIdx.x;
  int tot = 0;
#pragma unroll
  for (int s = 0; s < KS; ++s) tot += part[s * NQ + q];
  if (q < N) {
    float v = f2[q];
    perm[tot] = q;
    wsm[tot] = expf(0.2f * v);
    wbg[tot] = expf(v);
  } else {
    ksplit[q - N] = tot;
  }
}

// K3: per-chunk LOCAL scans (1 chunk per wave, registers only) + totals.
__global__ __launch_bounds__(256) void k3_scan(
    const float* __restrict__ h, const int* __restrict__ perm,
    const float* __restrict__ wsm, const float* __restrict__ wbg,
    float* __restrict__ Pl, float* __restrict__ Sl,
    float* __restrict__ pl, float* __restrict__ sl,
    float* __restrict__ tot_s, float* __restrict__ tot_b,
    float* __restrict__ tots_sc, float* __restrict__ totb_sc) {
  int t = threadIdx.x, lane = t & 63, wv = t >> 6;
  int c = blockIdx.x * 4 + wv;
  int base = c * CROWS;
  int dd = lane;
  int pj = (dd < CROWS) ? perm[base + dd] : 0;
  float wS = (dd < CROWS) ? wsm[base + dd] : 0.f;
  float wB = (dd < CROWS) ? wbg[base + dd] : 0.f;
  float hv[CROWS];
#pragma unroll
  for (int r = 0; r < CROWS; ++r) {
    int j = __shfl(pj, r);
    hv[r] = h[(size_t)j * D + dd];
  }
  // scalar weight scans over lanes 0..15
  float incS = wS, incB = wB;
#pragma unroll
  for (int off = 1; off < CROWS; off <<= 1) {
    float uS = __shfl_up(incS, off);
    float uB = __shfl_up(incB, off);
    if (dd >= off) { incS += uS; incB += uB; }
  }
  float totS = __shfl(incS, CROWS - 1);
  float totB = __shfl(incB, CROWS - 1);
  if (dd < CROWS) {
    pl[base + dd] = incS - wS;           // exclusive prefix (small w)
    sl[base + dd] = totB - (incB - wB);  // inclusive suffix (big w)
  }
  if (dd == 0) { tots_sc[c] = totS; totb_sc[c] = totB; }
  // vector local scans (registers only)
  float runP = 0.f;
#pragma unroll
  for (int r = 0; r < CROWS; ++r) {
    Pl[(size_t)(base + r) * D + dd] = runP;
    runP += __shfl(wS, r) * hv[r];
  }
  tot_s[c * D + dd] = runP;
  float runS = 0.f;
#pragma unroll
  for (int r = CROWS - 1; r >= 0; --r) {
    runS += __shfl(wB, r) * hv[r];
    Sl[(size_t)(base + r) * D + dd] = runS;
  }
  tot_b[c * D + dd] = runS;
}

// K3b: chunk-offset scans, fully parallel. Blocks 0..63: vector prefix for
// dim=blk; 64..127: vector exclusive suffix for dim=blk-64; 128: scalars.
// 512-wide Hillis-Steele in LDS (9 steps).
__global__ __launch_bounds__(512) void k3b_offsets(
    const float* __restrict__ tot_s, const float* __restrict__ tot_b,
    const float* __restrict__ tots_sc, const float* __restrict__ totb_sc,
    float* __restrict__ off_s, float* __restrict__ off_b,
    float* __restrict__ poff, float* __restrict__ soff,
    float* __restrict__ Pl, float* __restrict__ Sl,
    float* __restrict__ pl, float* __restrict__ sl) {
  __shared__ float sc[512];
  int t = threadIdx.x;
  int blk = blockIdx.x;
  if (blk < 64) {
    int dd = blk;
    float v = tot_s[t * D + dd];
    sc[t] = v;
    __syncthreads();
    float inc = v;
#pragma unroll
    for (int off = 1; off < 512; off <<= 1) {
      float u_ = (t >= off) ? sc[t - off] : 0.f;
      __syncthreads();
      inc += u_;
      sc[t] = inc;
      __syncthreads();
    }
    off_s[t * D + dd] = inc - v;
    if (t == 511) off_s[CHUNKS * D + dd] = inc;  // sentinel
    if (t == 0) Pl[(size_t)N * D + dd] = 0.f;
  } else if (blk < 128) {
    int dd = blk - 64;
    int rc = 511 - t;
    float v = tot_b[rc * D + dd];
    sc[t] = v;
    __syncthreads();
    float inc = v;
#pragma unroll
    for (int off = 1; off < 512; off <<= 1) {
      float u_ = (t >= off) ? sc[t - off] : 0.f;
      __syncthreads();
      inc += u_;
      sc[t] = inc;
      __syncthreads();
    }
    off_b[rc * D + dd] = inc - v;  // exclusive suffix
    if (t == 0) {
      off_b[CHUNKS * D + dd] = 0.f;  // sentinel
      Sl[(size_t)N * D + dd] = 0.f;
    }
  } else {
    {  // scalar prefix over tots_sc
      float v = tots_sc[t];
      sc[t] = v;
      __syncthreads();
      float inc = v;
#pragma unroll
      for (int off = 1; off < 512; off <<= 1) {
        float u_ = (t >= off) ? sc[t - off] : 0.f;
        __syncthreads();
        inc += u_;
        sc[t] = inc;
        __syncthreads();
      }
      poff[t] = inc - v;
      if (t == 511) poff[CHUNKS] = inc;
      if (t == 0) pl[N] = 0.f;
    }
    __syncthreads();
    {  // scalar exclusive suffix over totb_sc
      int rc = 511 - t;
      float v = totb_sc[rc];
      sc[t] = v;
      __syncthreads();
      float inc = v;
#pragma unroll
      for (int off = 1; off < 512; off <<= 1) {
        float u_ = (t >= off) ? sc[t - off] : 0.f;
        __syncthreads();
        inc += u_;
        sc[t] = inc;
        __syncthreads();
      }
      soff[rc] = inc - v;
      if (t == 0) {
        soff[CHUNKS] = 0.f;
        sl[N] = 0.f;
      }
    }
  }
}

// K4: per (row, dim): combine global offset + local scan at split k; ELU.
__global__ __launch_bounds__(256) void k4_out(
    const float* __restrict__ f1, const int* __restrict__ ksplit,
    const float* __restrict__ off_s, const float* __restrict__ off_b,
    const float* __restrict__ poff, const float* __restrict__ soff,
    const float* __restrict__ Pl, const float* __restrict__ Sl,
    const float* __restrict__ pl, const float* __restrict__ sl,
    float* __restrict__ out) {
  int g = blockIdx.x * 256 + threadIdx.x;
  int row = g >> 6, dd = g & 63;
  float f1v = f1[row];
  int k = ksplit[row];
  int c = k >> 4;  // CROWS == 16; k == N -> sentinel chunk
  float e1 = expf(f1v), e2 = expf(0.2f * f1v);
  float Sv = off_b[c * D + dd] + Sl[(size_t)k * D + dd];
  float Pv = off_s[c * D + dd] + Pl[(size_t)k * D + dd];
  float num = e1 * Sv + e2 * Pv;
  float den = e1 * (soff[c] + sl[k]) + e2 * (poff[c] + pl[k]);
  float v = num / den;
  out[g] = v > 0.f ? v : expm1f(v);
}

extern "C" void kernel_launch(void* const* d_in, const int* in_sizes, int n_in,
                              void* d_out, int out_size, void* d_ws,
                              size_t ws_size, hipStream_t stream) {
  const float* x = (const float*)d_in[0];
  const float* Wt = (const float*)d_in[1];
  const float* a1 = (const float*)d_in[2];
  const float* b1 = (const float*)d_in[3];
  const float* a2 = (const float*)d_in[4];
  const float* b2 = (const float*)d_in[5];
  float* out = (float*)d_out;

  u64* key64 = (u64*)d_ws;
  u64* thrkey = key64 + N;
  float* ws = (float*)(thrkey + N);
  float* h = ws;          ws += N * D;
  float* f1 = ws;         ws += N;
  float* f2v = ws;        ws += N;
  float* wsm = ws;        ws += N;
  float* wbg = ws;        ws += N;
  int* perm = (int*)ws;   ws += N;
  int* ksplit = (int*)ws; ws += N;
  int* part = (int*)ws;   ws += KS * NQ;
  float* Pl = ws;         ws += (size_t)(N + 1) * D;
  float* Sl = ws;         ws += (size_t)(N + 1) * D;
  float* tot_s = ws;      ws += CHUNKS * D;
  float* tot_b = ws;      ws += CHUNKS * D;
  float* off_s = ws;      ws += (CHUNKS + 1) * D;
  float* off_b = ws;      ws += (CHUNKS + 1) * D;
  float* pl = ws;         ws += (N + 1);
  float* sl = ws;         ws += (N + 1);
  float* tots_sc = ws;    ws += CHUNKS;
  float* totb_sc = ws;    ws += CHUNKS;
  float* poff = ws;       ws += (CHUNKS + 1);
  float* soff = ws;       ws += (CHUNKS + 1);

  k1_gemm<<<N / 16, 256, 0, stream>>>(x, Wt, a1, b1, a2, b2, h, f1, f2v,
                                      key64, thrkey);
  k2a_count<<<16 * KS, 256, 0, stream>>>(key64, thrkey, part);
  k2b_reduce<<<NQ / 256, 256, 0, stream>>>(part, f2v, perm, wsm, wbg, ksplit);
  k3_scan<<<CHUNKS / 4, 256, 0, stream>>>(h, perm, wsm, wbg, Pl, Sl, pl, sl,
                                          tot_s, tot_b, tots_sc, totb_sc);
  k3b_offsets<<<129, 512, 0, stream>>>(tot_s, tot_b, tots_sc, totb_sc, off_s,
                                       off_b, poff, soff, Pl, Sl, pl, sl);
  k4_out<<<(N * D) / 256, 256, 0, stream>>>(f1, ksplit, off_s, off_b, poff,
                                            soff, Pl, Sl, pl, sl, out);
}